// Round 13
// baseline (212.306 us; speedup 1.0000x reference)
//
#include <hip/hip_runtime.h>
#include <hip/hip_bf16.h>
#include <stdint.h>

// SRALayer R13: R12 + proj4 rebuilt as BK=32 ring-4 counted-vmcnt pipeline at the
// PROVEN register footprint: 256 thr / 128^2 tile / dynamic (not unrolled) loop /
// no sched_barrier. Depth-3 prefetch, vmcnt(12) steady state, 2-way-free swizzle
// (unit ^ (row>>1)&3). Everything else identical to R12 (200.2us).

#define B_ 8
#define S_ 2048
#define D_ 512
#define M_ (B_ * S_)
#define NSUB 64
#define SUBL 32
#define NSUP 8
#define SUPL 256

typedef __bf16 bf16x8 __attribute__((ext_vector_type(8)));
typedef float f32x4 __attribute__((ext_vector_type(4)));

__device__ __forceinline__ float bflo(uint32_t u){ return __uint_as_float(u<<16); }
__device__ __forceinline__ float bfhi(uint32_t u){ return __uint_as_float(u&0xffff0000u); }
__device__ __forceinline__ uint16_t f2bf(float f){
    uint32_t u = __float_as_uint(f);
    return (uint16_t)((u + 0x7fffu + ((u>>16)&1u)) >> 16);
}
__device__ __forceinline__ uint32_t pack2bf(float a, float b){
    return (uint32_t)f2bf(a) | ((uint32_t)f2bf(b)<<16);
}
__device__ __forceinline__ void gload16(const void* g, void* l){
    __builtin_amdgcn_global_load_lds(
        (const __attribute__((address_space(1))) uint32_t*)g,
        (__attribute__((address_space(3))) uint32_t*)l, 16, 0, 0);
}

// ---------------- convall: fp32 -> bf16 for x (ids 0..4095) and 5 weights ----------
__global__ __launch_bounds__(256) void convall(const float* __restrict__ x,
                                               const float* w0, const float* w1,
                                               const float* w2, const float* w3,
                                               const float* w4,
                                               uint16_t* __restrict__ xb,
                                               uint16_t* __restrict__ Wb){
    const int id = blockIdx.x;
    const float* in;
    uint16_t* out;
    size_t i;
    if (id < 4096) {
        in = x; out = xb;
        i = ((size_t)id*256 + threadIdx.x)*8;
    } else {
        const float* ws[5] = {w0,w1,w2,w3,w4};
        const int wid = (id - 4096) >> 7, off = (id - 4096) & 127;
        in = ws[wid]; out = Wb + (size_t)wid*D_*D_;
        i = ((size_t)off*256 + threadIdx.x)*8;
    }
    float4 a = *(const float4*)&in[i];
    float4 b = *(const float4*)&in[i+4];
    uint4 o; o.x=pack2bf(a.x,a.y); o.y=pack2bf(a.z,a.w); o.z=pack2bf(b.x,b.y); o.w=pack2bf(b.z,b.w);
    *(uint4*)&out[i] = o;
}

// ---------------- proj4: BK=32 ring-4 counted-vmcnt, 128^2 tile, 256 thr -----------
// grid (M_/128, 16). sect = by>>2 : 0=Q 1=K 2=V^T(swapped mfma) 3=G(sigmoid), bf16 out
__global__ __launch_bounds__(256) void proj4(const uint16_t* __restrict__ A,
                                             const uint16_t* __restrict__ Wb,
                                             const float* __restrict__ bq_,
                                             const float* __restrict__ bk_,
                                             const float* __restrict__ bv_,
                                             const float* __restrict__ bg_,
                                             uint16_t* __restrict__ Qb,
                                             uint16_t* __restrict__ Kb,
                                             uint16_t* __restrict__ VT,
                                             uint16_t* __restrict__ Gb)
{
    // 4 slots x (A 4096 | B 4096) uint16 = 64KB
    __shared__ __attribute__((aligned(16))) uint16_t SM[32768];
    const int tid = threadIdx.x, wave = tid>>6, lane = tid&63;
    const int m0 = blockIdx.x*128, n0 = blockIdx.y*128;
    const int wr = (wave>>1)*64, wc = (wave&1)*64;
    const int fr = lane&15, fq = lane>>4;
    const int sect = blockIdx.y >> 2;
    const int n0c = n0 & 511;
    const int rc = (fq ^ ((fr>>1)&3))*8;        // swizzled read unit (const per lane)
    f32x4 acc[4][4] = {};

    auto STAGE = [&](int ct, int s){            // 4 VMEM instrs / wave
        const int k0 = ct*32;
#pragma unroll
        for (int z = 0; z < 2; ++z) {
            const int ch  = z*256 + tid;        // 16B unit id 0..511
            const int row = ch >> 2, sl = ch & 3;
            const int kc  = (sl ^ ((row>>1)&3)) * 8;      // inverse swizzle on source
            const int ldsb = s*8192 + (z*256 + wave*64)*8; // linear dest, wave-uniform
            gload16(&A [(size_t)(m0+row)*D_ + k0 + kc], &SM[ldsb]);
            gload16(&Wb[(size_t)(n0+row)*D_ + k0 + kc], &SM[4096 + ldsb]);
        }
    };
    auto COMP = [&](int s){
        const int sb = s*8192;
        bf16x8 af[4], bfv[4];
#pragma unroll
        for (int m = 0; m < 4; ++m) af[m]  = *(const bf16x8*)&SM[sb + (wr+m*16+fr)*32 + rc];
#pragma unroll
        for (int n = 0; n < 4; ++n) bfv[n] = *(const bf16x8*)&SM[sb + 4096 + (wc+n*16+fr)*32 + rc];
        if (sect == 2) {
#pragma unroll
            for (int m = 0; m < 4; ++m)
#pragma unroll
                for (int n = 0; n < 4; ++n)
                    acc[m][n] = __builtin_amdgcn_mfma_f32_16x16x32_bf16(bfv[n], af[m], acc[m][n], 0,0,0);
        } else {
#pragma unroll
            for (int m = 0; m < 4; ++m)
#pragma unroll
                for (int n = 0; n < 4; ++n)
                    acc[m][n] = __builtin_amdgcn_mfma_f32_16x16x32_bf16(af[m], bfv[n], acc[m][n], 0,0,0);
        }
    };

    STAGE(0, 0); STAGE(1, 1); STAGE(2, 2);      // 12 loads in flight
#pragma unroll 1
    for (int i = 0; i < 16; ++i) {
        if (i < 13) {
            STAGE(i+3, (i+3)&3);                // 16 in flight
            asm volatile("s_waitcnt vmcnt(12)" ::: "memory");   // chunk i landed
        } else if (i == 13) {
            asm volatile("s_waitcnt vmcnt(8)" ::: "memory");
        } else if (i == 14) {
            asm volatile("s_waitcnt vmcnt(4)" ::: "memory");
        } else {
            asm volatile("s_waitcnt vmcnt(0)" ::: "memory");
        }
        __builtin_amdgcn_s_barrier();           // all waves' chunk-i data visible
        COMP(i & 3);
        __builtin_amdgcn_s_barrier();           // readers of slot done -> reusable
    }
    __syncthreads();                            // full fence before LDS reuse

    uint16_t (*L)[136] = (uint16_t(*)[136])&SM[0];
    const float* bias = (sect==0) ? bq_ : (sect==1) ? bk_ : (sect==2) ? bv_ : bg_;
    if (sect == 2) {                   // acc holds V^T[dv][t]
#pragma unroll
        for (int n = 0; n < 4; ++n)
#pragma unroll
            for (int q = 0; q < 4; ++q) {
                const int dvl = wc + n*16 + fq*4 + q;
                const float bvv = bias[n0c + dvl];
#pragma unroll
                for (int m = 0; m < 4; ++m)
                    L[dvl][wr + m*16 + fr] = f2bf(acc[m][n][q] + bvv);
            }
    } else {
#pragma unroll
        for (int n = 0; n < 4; ++n) {
            const int cl = wc + n*16 + fr;
            const float bvv = bias[n0c + cl];
#pragma unroll
            for (int m = 0; m < 4; ++m)
#pragma unroll
                for (int q = 0; q < 4; ++q) {
                    float c = acc[m][n][q] + bvv;
                    if (sect == 3) c = 1.f/(1.f + expf(-c));
                    L[wr + m*16 + fq*4 + q][cl] = f2bf(c);
                }
        }
    }
    __syncthreads();
    const int bb = m0 >> 11, t0 = m0 & 2047;
#pragma unroll
    for (int it = 0; it < 8; ++it) {
        const int r = it*16 + (tid>>4), c8 = (tid&15)*8;
        uint4 v = *(uint4*)&L[r][c8];
        if (sect == 0)      *(uint4*)&Qb[(size_t)(m0+r)*D_ + n0c + c8] = v;
        else if (sect == 1) *(uint4*)&Kb[(size_t)(m0+r)*D_ + n0c + c8] = v;
        else if (sect == 3) *(uint4*)&Gb[(size_t)(m0+r)*D_ + n0c + c8] = v;
        else                *(uint4*)&VT[((size_t)bb*D_ + n0c + r)*S_ + t0 + c8] = v;
    }
}

// ---------------- mfma_gemm: output projection (fp32 out), dbuf 2-phase ------------
__global__ __launch_bounds__(256) void mfma_gemm(const uint16_t* __restrict__ A,
                                                 const uint16_t* __restrict__ Wt,
                                                 const float* __restrict__ bias,
                                                 float* __restrict__ out)
{
    __shared__ __attribute__((aligned(16))) uint16_t SM[2][16384];
    const int tid = threadIdx.x, wave = tid>>6, lane = tid&63;
    const int m0 = blockIdx.x*128, n0 = blockIdx.y*128;
    const int wr = (wave>>1)*64, wc = (wave&1)*64;
    const int fr = lane&15, fq = lane>>4;
    f32x4 acc[4][4] = {};

    auto STAGE = [&](int kt, int p){
        const int k0 = kt*64;
#pragma unroll
        for (int i = 0; i < 4; ++i) {
            const int c = i*256 + tid;
            const int row = c>>3, kc = ((c&7) ^ (row&7))*8;
            const int ldsb = (i*256 + wave*64)*8;
            gload16(&A [(size_t)(m0+row)*D_ + k0 + kc], &SM[p][ldsb]);
            gload16(&Wt[(size_t)(n0+row)*D_ + k0 + kc], &SM[p][8192+ldsb]);
        }
    };
    auto COMP = [&](int p){
#pragma unroll
        for (int kk = 0; kk < 64; kk += 32) {
            const int sc = (kk + fq*8) ^ ((fr&7)<<3);
            bf16x8 af[4], bfv[4];
#pragma unroll
            for (int m = 0; m < 4; ++m) af[m]  = *(const bf16x8*)&SM[p][(wr+m*16+fr)*64 + sc];
#pragma unroll
            for (int n = 0; n < 4; ++n) bfv[n] = *(const bf16x8*)&SM[p][8192+(wc+n*16+fr)*64 + sc];
#pragma unroll
            for (int m = 0; m < 4; ++m)
#pragma unroll
                for (int n = 0; n < 4; ++n)
                    acc[m][n] = __builtin_amdgcn_mfma_f32_16x16x32_bf16(af[m], bfv[n], acc[m][n], 0,0,0);
        }
    };

    STAGE(0, 0);
    __syncthreads();
    int p = 0;
    for (int kt = 0; kt < 8; ++kt) {
        if (kt < 7) STAGE(kt+1, p^1);
        COMP(p);
        __syncthreads();
        p ^= 1;
    }

    float (*L32)[68] = (float(*)[68])&SM[0][0];
#pragma unroll
    for (int h = 0; h < 2; ++h) {
        if (wc == h*64) {
#pragma unroll
            for (int n = 0; n < 4; ++n) {
                const float bvv = bias[n0 + wc + n*16 + fr];
#pragma unroll
                for (int m = 0; m < 4; ++m)
#pragma unroll
                    for (int q = 0; q < 4; ++q)
                        L32[wr + m*16 + fq*4 + q][n*16 + fr] = acc[m][n][q] + bvv;
            }
        }
        __syncthreads();
#pragma unroll
        for (int it = 0; it < 8; ++it) {
            const int r = it*16 + (tid>>4), c4 = (tid&15)*4;
            *(uint4*)&out[(size_t)(m0+r)*D_ + n0 + h*64 + c4] = *(uint4*)&L32[r][c4];
        }
        __syncthreads();
    }
}

// ---------------- prep: LDS-free, bf16 gamma in ------------------------------------
__global__ __launch_bounds__(256) void prep(const uint16_t* __restrict__ Gb,
                                            uint16_t* __restrict__ Qb,
                                            uint16_t* __restrict__ Kb,
                                            uint16_t* __restrict__ KT,
                                            float* __restrict__ T)
{
    const int sub = blockIdx.x, b = blockIdx.y;
    const int tid = threadIdx.x;
    const int dk0 = tid*2;
    const size_t rowbase = ((size_t)b*S_ + sub*SUBL)*D_;
    const uint16_t* gp = Gb + rowbase + dk0;
    uint16_t*       qp = Qb + rowbase + dk0;
    uint16_t*       kp = Kb + rowbase + dk0;

    float mu0 = 1.f, mu1 = 1.f;
    uint32_t ksave[SUBL];
#pragma unroll
    for (int t = 0; t < SUBL; ++t) {
        const uint32_t g2 = *(const uint32_t*)(gp + (size_t)t*D_);
        const uint32_t qu = *(const uint32_t*)(qp + (size_t)t*D_);
        const uint32_t ku = *(const uint32_t*)(kp + (size_t)t*D_);
        mu0 = fmaxf(mu0*bflo(g2), 1e-30f);
        mu1 = fmaxf(mu1*bfhi(g2), 1e-30f);
        const float r0 = __builtin_amdgcn_rcpf(mu0);
        const float r1 = __builtin_amdgcn_rcpf(mu1);
        *(uint32_t*)(qp + (size_t)t*D_) = pack2bf(bflo(qu)*mu0, bfhi(qu)*mu1);
        const uint32_t kw = pack2bf(bflo(ku)*r0, bfhi(ku)*r1);
        *(uint32_t*)(kp + (size_t)t*D_) = kw;
        ksave[t] = kw;
    }
    T[((size_t)b*NSUB + sub)*D_ + dk0]     = mu0;
    T[((size_t)b*NSUB + sub)*D_ + dk0 + 1] = mu1;

    uint16_t* d0 = &KT[((size_t)b*D_ + dk0)*S_ + sub*SUBL];
    uint16_t* d1 = d0 + S_;
#pragma unroll
    for (int q4 = 0; q4 < 4; ++q4) {
        uint4 lo, hi;
        lo.x = (ksave[q4*8+0]&0xffffu) | (ksave[q4*8+1]<<16);
        lo.y = (ksave[q4*8+2]&0xffffu) | (ksave[q4*8+3]<<16);
        lo.z = (ksave[q4*8+4]&0xffffu) | (ksave[q4*8+5]<<16);
        lo.w = (ksave[q4*8+6]&0xffffu) | (ksave[q4*8+7]<<16);
        hi.x = (ksave[q4*8+0]>>16) | (ksave[q4*8+1]&0xffff0000u);
        hi.y = (ksave[q4*8+2]>>16) | (ksave[q4*8+3]&0xffff0000u);
        hi.z = (ksave[q4*8+4]>>16) | (ksave[q4*8+5]&0xffff0000u);
        hi.w = (ksave[q4*8+6]>>16) | (ksave[q4*8+7]&0xffff0000u);
        *(uint4*)&d0[q4*8] = lo;
        *(uint4*)&d1[q4*8] = hi;
    }
}

// ---------------- tables: Pre / Suf / Lam from T, grid (sp,b) ----------------------
__global__ __launch_bounds__(512) void tables(const float* __restrict__ T,
                                              float* __restrict__ Pre,
                                              float* __restrict__ Suf,
                                              float* __restrict__ Lam)
{
    const int sp = blockIdx.x, b = blockIdx.y, dk = threadIdx.x;
    float run = 1.f;
#pragma unroll
    for (int m = 0; m < 8; ++m) {
        Pre[((size_t)b*NSUB + sp*8+m)*D_ + dk] = run;
        run *= T[((size_t)b*NSUB + sp*8+m)*D_ + dk];
    }
    Lam[((size_t)b*NSUP + sp)*D_ + dk] = run;
    float rs = 1.f;
#pragma unroll
    for (int m = 7; m >= 0; --m) {
        rs *= T[((size_t)b*NSUB + sp*8+m)*D_ + dk];
        Suf[((size_t)b*NSUB + sp*8+m)*D_ + dk] = rs;
    }
}

// ---------------- pairsA: flat (i,j) grid, P_ij = Q~_i @ (D_ij * K^_j)^T -----------
__device__ __forceinline__ int swz(int r, int c){ return r*D_ + (c ^ ((r&7)<<3)); }

__global__ __launch_bounds__(256) void pairsA(const uint16_t* __restrict__ Qt,
                                              const uint16_t* __restrict__ Kh,
                                              const float* __restrict__ T,
                                              uint16_t* __restrict__ P)
{
    __shared__ __attribute__((aligned(16))) uint16_t qs[SUBL*D_];
    __shared__ __attribute__((aligned(16))) uint16_t ks[SUBL*D_];
    __shared__ float D_lds[D_];
    const int idx = blockIdx.x, sp = blockIdx.y, b = blockIdx.z;
    int i = 0;
    while (((i+1)*(i+2))/2 <= idx) ++i;
    const int j = idx - (i*(i+1))/2;

    const int tid = threadIdx.x, wave = tid>>6, lane = tid&63;
    const int fr = lane&15, fq = lane>>4;
    const int mq = wave>>1, nq = wave&1;
    const size_t qrow = (size_t)b*S_ + sp*SUPL + i*SUBL;
    const size_t krow = (size_t)b*S_ + sp*SUPL + j*SUBL;
    const size_t prow = ((size_t)(b*NSUP + sp)*SUPL + i*SUBL);

#pragma unroll
    for (int z = 0; z < 8; ++z) {
        int ch = z*256 + tid, r = ch>>6, c = (ch&63)*8;
        *(uint4*)&qs[swz(r,c)] = *(const uint4*)&Qt[(qrow + r)*D_ + c];
    }
    const int dkA = tid*2, dkB = tid*2+1;
    float d0 = 1.f, d1 = 1.f;
    for (int m = j; m < i; ++m) {
        d0 *= T[((size_t)b*NSUB + sp*8 + m)*D_ + dkA];
        d1 *= T[((size_t)b*NSUB + sp*8 + m)*D_ + dkB];
    }
    D_lds[dkA] = d0; D_lds[dkB] = d1;
    __syncthreads();

#pragma unroll
    for (int z = 0; z < 8; ++z) {
        int ch = z*256 + tid, r = ch>>6, c = (ch&63)*8;
        uint4 u = *(const uint4*)&Kh[(krow + r)*D_ + c];
        uint4 o;
        o.x = pack2bf(bflo(u.x)*D_lds[c+0], bfhi(u.x)*D_lds[c+1]);
        o.y = pack2bf(bflo(u.y)*D_lds[c+2], bfhi(u.y)*D_lds[c+3]);
        o.z = pack2bf(bflo(u.z)*D_lds[c+4], bfhi(u.z)*D_lds[c+5]);
        o.w = pack2bf(bflo(u.w)*D_lds[c+6], bfhi(u.w)*D_lds[c+7]);
        *(uint4*)&ks[swz(r,c)] = o;
    }
    __syncthreads();

    f32x4 a0 = {}, a1 = {}, a2 = {}, a3 = {};
#pragma unroll
    for (int kk = 0; kk < 512; kk += 128) {
        bf16x8 q0 = *(const bf16x8*)&qs[swz(mq*16+fr, kk      + fq*8)];
        bf16x8 k0 = *(const bf16x8*)&ks[swz(nq*16+fr, kk      + fq*8)];
        bf16x8 q1 = *(const bf16x8*)&qs[swz(mq*16+fr, kk + 32 + fq*8)];
        bf16x8 k1 = *(const bf16x8*)&ks[swz(nq*16+fr, kk + 32 + fq*8)];
        bf16x8 q2 = *(const bf16x8*)&qs[swz(mq*16+fr, kk + 64 + fq*8)];
        bf16x8 k2 = *(const bf16x8*)&ks[swz(nq*16+fr, kk + 64 + fq*8)];
        bf16x8 q3 = *(const bf16x8*)&qs[swz(mq*16+fr, kk + 96 + fq*8)];
        bf16x8 k3 = *(const bf16x8*)&ks[swz(nq*16+fr, kk + 96 + fq*8)];
        a0 = __builtin_amdgcn_mfma_f32_16x16x32_bf16(q0, k0, a0, 0,0,0);
        a1 = __builtin_amdgcn_mfma_f32_16x16x32_bf16(q1, k1, a1, 0,0,0);
        a2 = __builtin_amdgcn_mfma_f32_16x16x32_bf16(q2, k2, a2, 0,0,0);
        a3 = __builtin_amdgcn_mfma_f32_16x16x32_bf16(q3, k3, a3, 0,0,0);
    }
    const int ul = nq*16 + fr;
#pragma unroll
    for (int q_ = 0; q_ < 4; ++q_) {
        const int tl = mq*16 + fq*4 + q_;
        float v = a0[q_] + a1[q_] + a2[q_] + a3[q_];
        if (i == j && ul > tl) v = 0.f;
        P[(prow + tl)*SUPL + j*SUBL + ul] = f2bf(v);
    }
}

// ---------------- dsgemm: dbuf 2-phase, dS_c = sum_u (Suf*k^_u) v_u^T --------------
__global__ __launch_bounds__(256) void dsgemm(const uint16_t* __restrict__ VT,
                                              const uint16_t* __restrict__ KT,
                                              const float* __restrict__ Suf,
                                              uint16_t* __restrict__ Sst)
{
    __shared__ __attribute__((aligned(16))) uint16_t As[2][128][40];
    __shared__ __attribute__((aligned(16))) uint16_t Bs[2][128][40];
    const int tile = blockIdx.x, c = blockIdx.y, b = blockIdx.z;
    const int m0 = (tile&3)*128, n0 = (tile>>2)*128;
    const int tid = threadIdx.x, wave = tid>>6, lane = tid&63;
    const int wr = (wave>>1)*64, wc = (wave&1)*64;
    const int fr = lane&15, fq = lane>>4;
    f32x4 acc[4][4] = {};

    auto STAGE = [&](int j, int p){
        const int t0 = c*SUPL + j*SUBL;
#pragma unroll
        for (int ch = tid; ch < 512; ch += 256) {
            int row = ch>>2, tc = (ch&3)*8;
            *(uint4*)&As[p][row][tc] = *(const uint4*)&VT[((size_t)b*D_ + m0+row)*S_ + t0 + tc];
        }
#pragma unroll
        for (int ch = tid; ch < 512; ch += 256) {
            int row = ch>>2, tc = (ch&3)*8;
            uint4 u = *(const uint4*)&KT[((size_t)b*D_ + n0+row)*S_ + t0 + tc];
            float sf = Suf[((size_t)b*NSUB + c*8 + j)*D_ + n0 + row];
            uint4 o;
            o.x = pack2bf(bflo(u.x)*sf, bfhi(u.x)*sf);
            o.y = pack2bf(bflo(u.y)*sf, bfhi(u.y)*sf);
            o.z = pack2bf(bflo(u.z)*sf, bfhi(u.z)*sf);
            o.w = pack2bf(bflo(u.w)*sf, bfhi(u.w)*sf);
            *(uint4*)&Bs[p][row][tc] = o;
        }
    };

    STAGE(0, 0);
    __syncthreads();
    int p = 0;
    for (int j = 0; j < 8; ++j) {
        if (j < 7) STAGE(j+1, p^1);
        bf16x8 af[4], bf[4];
#pragma unroll
        for (int m = 0; m < 4; ++m) af[m] = *(const bf16x8*)&As[p][wr+m*16+fr][fq*8];
#pragma unroll
        for (int n = 0; n < 4; ++n) bf[n] = *(const bf16x8*)&Bs[p][wc+n*16+fr][fq*8];
#pragma unroll
        for (int m = 0; m < 4; ++m)
#pragma unroll
            for (int n = 0; n < 4; ++n)
                acc[m][n] = __builtin_amdgcn_mfma_f32_16x16x32_bf16(af[m], bf[n], acc[m][n], 0,0,0);
        __syncthreads();
        p ^= 1;
    }
#pragma unroll
    for (int n = 0; n < 4; ++n) {
        const int dk = n0 + wc + n*16 + fr;
#pragma unroll
        for (int m = 0; m < 4; ++m)
#pragma unroll
            for (int q = 0; q < 4; ++q) {
                const int dv = m0 + wr + m*16 + fq*4 + q;
                Sst[(((size_t)c*B_ + b)*D_ + dv)*D_ + dk] = f2bf(acc[m][n][q]);
            }
    }
}

// ---------------- scanfix: S_c = Lam_c (x) S_{c-1} + dS_c, c = 1..6 ----------------
__global__ __launch_bounds__(256) void scanfix(uint16_t* __restrict__ Sst,
                                               const float* __restrict__ Lam)
{
    const int id = blockIdx.x*256 + threadIdx.x;
    const int g = id & 63, dv = (id>>6) & 511, b = id >> 15;
    const int dk = g*8;
    float s[8];
    {
        uint4 u = *(const uint4*)&Sst[(((size_t)0*B_ + b)*D_ + dv)*D_ + dk];
        s[0]=bflo(u.x); s[1]=bfhi(u.x); s[2]=bflo(u.y); s[3]=bfhi(u.y);
        s[4]=bflo(u.z); s[5]=bfhi(u.z); s[6]=bflo(u.w); s[7]=bfhi(u.w);
    }
    for (int c = 1; c < 7; ++c) {
        const size_t bs = (((size_t)c*B_ + b)*D_ + dv)*D_ + dk;
        uint4 d = *(const uint4*)&Sst[bs];
        float4 l0 = *(const float4*)&Lam[((size_t)b*NSUP + c)*D_ + dk];
        float4 l1 = *(const float4*)&Lam[((size_t)b*NSUP + c)*D_ + dk + 4];
        s[0] = l0.x*s[0] + bflo(d.x); s[1] = l0.y*s[1] + bfhi(d.x);
        s[2] = l0.z*s[2] + bflo(d.y); s[3] = l0.w*s[3] + bfhi(d.y);
        s[4] = l1.x*s[4] + bflo(d.z); s[5] = l1.y*s[5] + bfhi(d.z);
        s[6] = l1.z*s[6] + bflo(d.w); s[7] = l1.w*s[7] + bfhi(d.w);
        uint4 o;
        o.x = pack2bf(s[0],s[1]); o.y = pack2bf(s[2],s[3]);
        o.z = pack2bf(s[4],s[5]); o.w = pack2bf(s[6],s[7]);
        *(uint4*)&Sst[bs] = o;
    }
}

// ---------------- bigout: O = [Q~*Pre | P] @ [S_prev ; V], dbuf, upper-tri masked --
__global__ __launch_bounds__(256) void bigout(const uint16_t* __restrict__ Qt,
                                              const float* __restrict__ Pre,
                                              const uint16_t* __restrict__ Sst,
                                              const uint16_t* __restrict__ Pb,
                                              const uint16_t* __restrict__ VT,
                                              uint16_t* __restrict__ O)
{
    __shared__ __attribute__((aligned(16))) uint16_t SM[2][16384];
    __shared__ float PreL[4*512];
    const int m0 = blockIdx.x*128, n0 = blockIdx.y*128;
    const int b = blockIdx.z>>3, sp = blockIdx.z&7;
    const int tid = threadIdx.x, wave = tid>>6, lane = tid&63;
    const int wr = (wave>>1)*64, wc = (wave&1)*64;
    const int fr = lane&15, fq = lane>>4;
    const int i0 = m0>>5;

#pragma unroll
    for (int z = 0; z < 8; ++z) {
        int idx = z*256 + tid;
        PreL[idx] = Pre[((size_t)b*NSUB + sp*8 + i0 + (idx>>9))*D_ + (idx&511)];
    }
    f32x4 acc[4][4] = {};
    uint4 areg[4];

    auto ISSUE_A = [&](int kt){
        const int k0 = kt*64;
#pragma unroll
        for (int z = 0; z < 4; ++z) {
            int ch = z*256 + tid, r = ch>>3, cc = (ch&7)*8;
            areg[z] = *(const uint4*)&Qt[((size_t)b*S_ + sp*SUPL + m0 + r)*D_ + k0 + cc];
        }
    };
    auto WRITE_A = [&](int kt, int p){
        const int k0 = kt*64;
#pragma unroll
        for (int z = 0; z < 4; ++z) {
            int ch = z*256 + tid, r = ch>>3, cc = (ch&7)*8;
            const float* pr = &PreL[((r>>5)<<9) + k0 + cc];
            uint4 u = areg[z];
            uint4 o;
            o.x = pack2bf(bflo(u.x)*pr[0], bfhi(u.x)*pr[1]);
            o.y = pack2bf(bflo(u.y)*pr[2], bfhi(u.y)*pr[3]);
            o.z = pack2bf(bflo(u.z)*pr[4], bfhi(u.z)*pr[5]);
            o.w = pack2bf(bflo(u.w)*pr[6], bfhi(u.w)*pr[7]);
            *(uint4*)&SM[p][r*64 + (cc ^ ((r&7)<<3))] = o;
        }
    };
    auto STAGE_A_GL = [&](int kt, int p){
        const int u0 = (kt-8)*64;
#pragma unroll
        for (int z = 0; z < 4; ++z) {
            int ch = z*256 + tid, row = ch>>3, kc = ((ch&7) ^ (row&7))*8;
            int ldsb = (z*256 + wave*64)*8;
            gload16(&Pb[((size_t)(b*NSUP + sp)*SUPL + m0 + row)*SUPL + u0 + kc], &SM[p][ldsb]);
        }
    };
    auto STAGE_B = [&](int kt, int p){
        if (kt < 8) {
            const int k0 = kt*64;
#pragma unroll
            for (int z = 0; z < 4; ++z) {
                int ch = z*256 + tid, row = ch>>3, kc = ((ch&7) ^ (row&7))*8;
                int ldsb = (z*256 + wave*64)*8;
                gload16(&Sst[(((size_t)(sp-1)*B_ + b)*D_ + n0 + row)*D_ + k0 + kc], &SM[p][8192+ldsb]);
            }
        } else {
            const int u0 = (kt-8)*64;
#pragma unroll
            for (int z = 0; z < 4; ++z) {
                int ch = z*256 + tid, row = ch>>3, kc = ((ch&7) ^ (row&7))*8;
                int ldsb = (z*256 + wave*64)*8;
                gload16(&VT[((size_t)b*D_ + n0 + row)*S_ + sp*SUPL + u0 + kc], &SM[p][8192+ldsb]);
            }
        }
    };
    auto COMP = [&](int p, int kt){
        const bf16x8 zz = {};
#pragma unroll
        for (int kk = 0; kk < 64; kk += 32) {
            const int sc = (kk + fq*8) ^ ((fr&7)<<3);
            bf16x8 af[4], bfv[4];
#pragma unroll
            for (int m = 0; m < 4; ++m) af[m] = *(const bf16x8*)&SM[p][(wr+m*16+fr)*64 + sc];
            if (kt >= 8) {
                const int jb = ((kt-8)*64 + kk) >> 5;
#pragma unroll
                for (int m = 0; m < 4; ++m) {
                    const int ib = (m0 + wr + m*16) >> 5;
                    if (jb > ib) af[m] = zz;
                }
            }
#pragma unroll
            for (int n = 0; n < 4; ++n) bfv[n] = *(const bf16x8*)&SM[p][8192+(wc+n*16+fr)*64 + sc];
#pragma unroll
            for (int m = 0; m < 4; ++m)
#pragma unroll
                for (int n = 0; n < 4; ++n)
                    acc[m][n] = __builtin_amdgcn_mfma_f32_16x16x32_bf16(af[m], bfv[n], acc[m][n], 0,0,0);
        }
    };

    const int kt0 = (sp == 0) ? 8 : 0;
    if (kt0 < 8) {
        ISSUE_A(kt0);
        STAGE_B(kt0, 0);
        __syncthreads();
        WRITE_A(kt0, 0);
    } else {
        STAGE_A_GL(kt0, 0);
        STAGE_B(kt0, 0);
    }
    __syncthreads();

    int p = 0;
    for (int kt = kt0; kt < 12; ++kt) {
        const int nxt = kt + 1;
        if (nxt < 12) {
            if (nxt < 8) ISSUE_A(nxt); else STAGE_A_GL(nxt, p^1);
            STAGE_B(nxt, p^1);
        }
        COMP(p, kt);
        if (nxt < 12 && nxt < 8) WRITE_A(nxt, p^1);
        __syncthreads();
        p ^= 1;
    }

    uint16_t (*L)[136] = (uint16_t(*)[136])&SM[0][0];
#pragma unroll
    for (int n = 0; n < 4; ++n) {
        const int cl = wc + n*16 + fr;
#pragma unroll
        for (int m = 0; m < 4; ++m)
#pragma unroll
            for (int q = 0; q < 4; ++q)
                L[wr + m*16 + fq*4 + q][cl] = f2bf(acc[m][n][q]);
    }
    __syncthreads();
#pragma unroll
    for (int it = 0; it < 8; ++it) {
        const int r = it*16 + (tid>>4), c8 = (tid&15)*8;
        *(uint4*)&O[((size_t)b*S_ + sp*SUPL + m0 + r)*D_ + n0 + c8] = *(uint4*)&L[r][c8];
    }
}

// ---------------- launch ----------------------------------------------------------
extern "C" void kernel_launch(void* const* d_in, const int* in_sizes, int n_in,
                              void* d_out, int out_size, void* d_ws, size_t ws_size,
                              hipStream_t stream)
{
    (void)in_sizes; (void)n_in; (void)out_size; (void)ws_size;
    const float* x  = (const float*)d_in[0];
    const float* Wq = (const float*)d_in[1];  const float* bq = (const float*)d_in[2];
    const float* Wk = (const float*)d_in[3];  const float* bk = (const float*)d_in[4];
    const float* Wv = (const float*)d_in[5];  const float* bv = (const float*)d_in[6];
    const float* Wg = (const float*)d_in[7];  const float* bg = (const float*)d_in[8];
    const float* Wo = (const float*)d_in[9];  const float* bo = (const float*)d_in[10];

    char* w = (char*)d_ws;
    const size_t MD2 = (size_t)M_*D_*2;
    uint16_t* Wb = (uint16_t*)w;                       w += 5*(size_t)D_*D_*2;
    uint16_t* xb = (uint16_t*)w;                       w += MD2;                  // x, later O
    uint16_t* Qb = (uint16_t*)w;                       w += MD2;                  // Q -> Q~
    uint16_t* Kb = (uint16_t*)w;                       w += MD2;                  // K -> K^ rows
    uint16_t* KT = (uint16_t*)w;                       w += MD2;                  // K^T [b][dk][t]
    uint16_t* VT = (uint16_t*)w;                       w += MD2;                  // V^T [b][dv][t]
    uint16_t* Gb = (uint16_t*)w;                       w += MD2;                  // gamma bf16
    uint16_t* Sst = (uint16_t*)w;                      w += (size_t)7*B_*D_*D_*2;
    uint16_t* Pb  = (uint16_t*)w;                      w += (size_t)B_*NSUP*SUPL*SUPL*2;
    float*    T   = (float*)w;                         w += (size_t)B_*NSUB*D_*4;
    float*    Pre = (float*)w;                         w += (size_t)B_*NSUB*D_*4;
    float*    Suf = (float*)w;                         w += (size_t)B_*NSUB*D_*4;
    float*    Lam = (float*)w;                         w += (size_t)B_*NSUP*D_*4;

    convall<<<dim3(4096 + 5*128), 256, 0, stream>>>(x, Wq, Wk, Wv, Wg, Wo, xb, Wb);

    proj4<<<dim3(M_/128, 16), 256, 0, stream>>>(xb, Wb, bq, bk, bv, bg, Qb, Kb, VT, Gb);

    prep<<<dim3(NSUB, B_), 256, 0, stream>>>(Gb, Qb, Kb, KT, T);
    tables<<<dim3(NSUP, B_), 512, 0, stream>>>(T, Pre, Suf, Lam);

    pairsA<<<dim3(36, NSUP, B_), 256, 0, stream>>>(Qb, Kb, T, Pb);
    dsgemm<<<dim3(16, 7, B_), 256, 0, stream>>>(VT, KT, Suf, Sst);
    scanfix<<<dim3(1024), 256, 0, stream>>>(Sst, Lam);

    bigout<<<dim3(2, 4, B_*NSUP), 256, 0, stream>>>(Qb, Pre, Sst, Pb, VT, xb);

    mfma_gemm<<<dim3(M_/128, D_/128), 256, 0, stream>>>(xb, Wb + 4*(size_t)D_*D_, bo, (float*)d_out);
}

// Round 14
// 200.129 us; speedup vs baseline: 1.0608x; 1.0608x over previous
//
#include <hip/hip_runtime.h>
#include <hip/hip_bf16.h>
#include <stdint.h>

// SRALayer R14 == R12 exactly (best measured: 200.2us). R13's BK=32 ring regressed
// (16 MFMA/barrier-pair vs 64 -> 4x barrier+VALU overhead; MfmaUtil 19.5%). The
// counted-vmcnt family is exhausted (R8 null / R9-R10 spill / R13 ratio): final config.

#define B_ 8
#define S_ 2048
#define D_ 512
#define M_ (B_ * S_)
#define NSUB 64
#define SUBL 32
#define NSUP 8
#define SUPL 256

typedef __bf16 bf16x8 __attribute__((ext_vector_type(8)));
typedef float f32x4 __attribute__((ext_vector_type(4)));

__device__ __forceinline__ float bflo(uint32_t u){ return __uint_as_float(u<<16); }
__device__ __forceinline__ float bfhi(uint32_t u){ return __uint_as_float(u&0xffff0000u); }
__device__ __forceinline__ uint16_t f2bf(float f){
    uint32_t u = __float_as_uint(f);
    return (uint16_t)((u + 0x7fffu + ((u>>16)&1u)) >> 16);
}
__device__ __forceinline__ uint32_t pack2bf(float a, float b){
    return (uint32_t)f2bf(a) | ((uint32_t)f2bf(b)<<16);
}
__device__ __forceinline__ void gload16(const void* g, void* l){
    __builtin_amdgcn_global_load_lds(
        (const __attribute__((address_space(1))) uint32_t*)g,
        (__attribute__((address_space(3))) uint32_t*)l, 16, 0, 0);
}

// ---------------- convall: fp32 -> bf16 for x (ids 0..4095) and 5 weights ----------
__global__ __launch_bounds__(256) void convall(const float* __restrict__ x,
                                               const float* w0, const float* w1,
                                               const float* w2, const float* w3,
                                               const float* w4,
                                               uint16_t* __restrict__ xb,
                                               uint16_t* __restrict__ Wb){
    const int id = blockIdx.x;
    const float* in;
    uint16_t* out;
    size_t i;
    if (id < 4096) {
        in = x; out = xb;
        i = ((size_t)id*256 + threadIdx.x)*8;
    } else {
        const float* ws[5] = {w0,w1,w2,w3,w4};
        const int wid = (id - 4096) >> 7, off = (id - 4096) & 127;
        in = ws[wid]; out = Wb + (size_t)wid*D_*D_;
        i = ((size_t)off*256 + threadIdx.x)*8;
    }
    float4 a = *(const float4*)&in[i];
    float4 b = *(const float4*)&in[i+4];
    uint4 o; o.x=pack2bf(a.x,a.y); o.y=pack2bf(a.z,a.w); o.z=pack2bf(b.x,b.y); o.w=pack2bf(b.z,b.w);
    *(uint4*)&out[i] = o;
}

// ---------------- proj4: fused Q|K|V|G GEMM, dbuf 2-phase --------------------------
// grid (M_/128, 16). sect = by>>2 : 0=Q 1=K 2=V^T(swapped mfma) 3=G(sigmoid), bf16 out
__global__ __launch_bounds__(256) void proj4(const uint16_t* __restrict__ A,
                                             const uint16_t* __restrict__ Wb,
                                             const float* __restrict__ bq_,
                                             const float* __restrict__ bk_,
                                             const float* __restrict__ bv_,
                                             const float* __restrict__ bg_,
                                             uint16_t* __restrict__ Qb,
                                             uint16_t* __restrict__ Kb,
                                             uint16_t* __restrict__ VT,
                                             uint16_t* __restrict__ Gb)
{
    __shared__ __attribute__((aligned(16))) uint16_t SM[2][16384];
    const int tid = threadIdx.x, wave = tid>>6, lane = tid&63;
    const int m0 = blockIdx.x*128, n0 = blockIdx.y*128;
    const int wr = (wave>>1)*64, wc = (wave&1)*64;
    const int fr = lane&15, fq = lane>>4;
    const int sect = blockIdx.y >> 2;
    const int n0c = n0 & 511;
    f32x4 acc[4][4] = {};

    auto STAGE = [&](int kt, int p){
        const int k0 = kt*64;
#pragma unroll
        for (int i = 0; i < 4; ++i) {
            const int c = i*256 + tid;
            const int row = c>>3, kc = ((c&7) ^ (row&7))*8;
            const int ldsb = (i*256 + wave*64)*8;
            gload16(&A [(size_t)(m0+row)*D_ + k0 + kc], &SM[p][ldsb]);
            gload16(&Wb[(size_t)(n0+row)*D_ + k0 + kc], &SM[p][8192+ldsb]);
        }
    };
    auto COMP = [&](int p){
#pragma unroll
        for (int kk = 0; kk < 64; kk += 32) {
            const int sc = (kk + fq*8) ^ ((fr&7)<<3);
            bf16x8 af[4], bfv[4];
#pragma unroll
            for (int m = 0; m < 4; ++m) af[m]  = *(const bf16x8*)&SM[p][(wr+m*16+fr)*64 + sc];
#pragma unroll
            for (int n = 0; n < 4; ++n) bfv[n] = *(const bf16x8*)&SM[p][8192+(wc+n*16+fr)*64 + sc];
            if (sect == 2) {
#pragma unroll
                for (int m = 0; m < 4; ++m)
#pragma unroll
                    for (int n = 0; n < 4; ++n)
                        acc[m][n] = __builtin_amdgcn_mfma_f32_16x16x32_bf16(bfv[n], af[m], acc[m][n], 0,0,0);
            } else {
#pragma unroll
                for (int m = 0; m < 4; ++m)
#pragma unroll
                    for (int n = 0; n < 4; ++n)
                        acc[m][n] = __builtin_amdgcn_mfma_f32_16x16x32_bf16(af[m], bfv[n], acc[m][n], 0,0,0);
            }
        }
    };

    STAGE(0, 0);
    __syncthreads();
    int p = 0;
    for (int kt = 0; kt < 8; ++kt) {
        if (kt < 7) STAGE(kt+1, p^1);
        COMP(p);
        __syncthreads();
        p ^= 1;
    }

    uint16_t (*L)[136] = (uint16_t(*)[136])&SM[0][0];
    const float* bias = (sect==0) ? bq_ : (sect==1) ? bk_ : (sect==2) ? bv_ : bg_;
    if (sect == 2) {                   // acc holds V^T[dv][t]
#pragma unroll
        for (int n = 0; n < 4; ++n)
#pragma unroll
            for (int q = 0; q < 4; ++q) {
                const int dvl = wc + n*16 + fq*4 + q;
                const float bvv = bias[n0c + dvl];
#pragma unroll
                for (int m = 0; m < 4; ++m)
                    L[dvl][wr + m*16 + fr] = f2bf(acc[m][n][q] + bvv);
            }
    } else {
#pragma unroll
        for (int n = 0; n < 4; ++n) {
            const int cl = wc + n*16 + fr;
            const float bvv = bias[n0c + cl];
#pragma unroll
            for (int m = 0; m < 4; ++m)
#pragma unroll
                for (int q = 0; q < 4; ++q) {
                    float c = acc[m][n][q] + bvv;
                    if (sect == 3) c = 1.f/(1.f + expf(-c));
                    L[wr + m*16 + fq*4 + q][cl] = f2bf(c);
                }
        }
    }
    __syncthreads();
    const int bb = m0 >> 11, t0 = m0 & 2047;
#pragma unroll
    for (int it = 0; it < 8; ++it) {
        const int r = it*16 + (tid>>4), c8 = (tid&15)*8;
        uint4 v = *(uint4*)&L[r][c8];
        if (sect == 0)      *(uint4*)&Qb[(size_t)(m0+r)*D_ + n0c + c8] = v;
        else if (sect == 1) *(uint4*)&Kb[(size_t)(m0+r)*D_ + n0c + c8] = v;
        else if (sect == 3) *(uint4*)&Gb[(size_t)(m0+r)*D_ + n0c + c8] = v;
        else                *(uint4*)&VT[((size_t)bb*D_ + n0c + r)*S_ + t0 + c8] = v;
    }
}

// ---------------- mfma_gemm: output projection (fp32 out), dbuf 2-phase ------------
__global__ __launch_bounds__(256) void mfma_gemm(const uint16_t* __restrict__ A,
                                                 const uint16_t* __restrict__ Wt,
                                                 const float* __restrict__ bias,
                                                 float* __restrict__ out)
{
    __shared__ __attribute__((aligned(16))) uint16_t SM[2][16384];
    const int tid = threadIdx.x, wave = tid>>6, lane = tid&63;
    const int m0 = blockIdx.x*128, n0 = blockIdx.y*128;
    const int wr = (wave>>1)*64, wc = (wave&1)*64;
    const int fr = lane&15, fq = lane>>4;
    f32x4 acc[4][4] = {};

    auto STAGE = [&](int kt, int p){
        const int k0 = kt*64;
#pragma unroll
        for (int i = 0; i < 4; ++i) {
            const int c = i*256 + tid;
            const int row = c>>3, kc = ((c&7) ^ (row&7))*8;
            const int ldsb = (i*256 + wave*64)*8;
            gload16(&A [(size_t)(m0+row)*D_ + k0 + kc], &SM[p][ldsb]);
            gload16(&Wt[(size_t)(n0+row)*D_ + k0 + kc], &SM[p][8192+ldsb]);
        }
    };
    auto COMP = [&](int p){
#pragma unroll
        for (int kk = 0; kk < 64; kk += 32) {
            const int sc = (kk + fq*8) ^ ((fr&7)<<3);
            bf16x8 af[4], bfv[4];
#pragma unroll
            for (int m = 0; m < 4; ++m) af[m]  = *(const bf16x8*)&SM[p][(wr+m*16+fr)*64 + sc];
#pragma unroll
            for (int n = 0; n < 4; ++n) bfv[n] = *(const bf16x8*)&SM[p][8192+(wc+n*16+fr)*64 + sc];
#pragma unroll
            for (int m = 0; m < 4; ++m)
#pragma unroll
                for (int n = 0; n < 4; ++n)
                    acc[m][n] = __builtin_amdgcn_mfma_f32_16x16x32_bf16(af[m], bfv[n], acc[m][n], 0,0,0);
        }
    };

    STAGE(0, 0);
    __syncthreads();
    int p = 0;
    for (int kt = 0; kt < 8; ++kt) {
        if (kt < 7) STAGE(kt+1, p^1);
        COMP(p);
        __syncthreads();
        p ^= 1;
    }

    float (*L32)[68] = (float(*)[68])&SM[0][0];
#pragma unroll
    for (int h = 0; h < 2; ++h) {
        if (wc == h*64) {
#pragma unroll
            for (int n = 0; n < 4; ++n) {
                const float bvv = bias[n0 + wc + n*16 + fr];
#pragma unroll
                for (int m = 0; m < 4; ++m)
#pragma unroll
                    for (int q = 0; q < 4; ++q)
                        L32[wr + m*16 + fq*4 + q][n*16 + fr] = acc[m][n][q] + bvv;
            }
        }
        __syncthreads();
#pragma unroll
        for (int it = 0; it < 8; ++it) {
            const int r = it*16 + (tid>>4), c4 = (tid&15)*4;
            *(uint4*)&out[(size_t)(m0+r)*D_ + n0 + h*64 + c4] = *(uint4*)&L32[r][c4];
        }
        __syncthreads();
    }
}

// ---------------- prep: LDS-free, bf16 gamma in ------------------------------------
__global__ __launch_bounds__(256) void prep(const uint16_t* __restrict__ Gb,
                                            uint16_t* __restrict__ Qb,
                                            uint16_t* __restrict__ Kb,
                                            uint16_t* __restrict__ KT,
                                            float* __restrict__ T)
{
    const int sub = blockIdx.x, b = blockIdx.y;
    const int tid = threadIdx.x;
    const int dk0 = tid*2;
    const size_t rowbase = ((size_t)b*S_ + sub*SUBL)*D_;
    const uint16_t* gp = Gb + rowbase + dk0;
    uint16_t*       qp = Qb + rowbase + dk0;
    uint16_t*       kp = Kb + rowbase + dk0;

    float mu0 = 1.f, mu1 = 1.f;
    uint32_t ksave[SUBL];
#pragma unroll
    for (int t = 0; t < SUBL; ++t) {
        const uint32_t g2 = *(const uint32_t*)(gp + (size_t)t*D_);
        const uint32_t qu = *(const uint32_t*)(qp + (size_t)t*D_);
        const uint32_t ku = *(const uint32_t*)(kp + (size_t)t*D_);
        mu0 = fmaxf(mu0*bflo(g2), 1e-30f);
        mu1 = fmaxf(mu1*bfhi(g2), 1e-30f);
        const float r0 = __builtin_amdgcn_rcpf(mu0);
        const float r1 = __builtin_amdgcn_rcpf(mu1);
        *(uint32_t*)(qp + (size_t)t*D_) = pack2bf(bflo(qu)*mu0, bfhi(qu)*mu1);
        const uint32_t kw = pack2bf(bflo(ku)*r0, bfhi(ku)*r1);
        *(uint32_t*)(kp + (size_t)t*D_) = kw;
        ksave[t] = kw;
    }
    T[((size_t)b*NSUB + sub)*D_ + dk0]     = mu0;
    T[((size_t)b*NSUB + sub)*D_ + dk0 + 1] = mu1;

    uint16_t* d0 = &KT[((size_t)b*D_ + dk0)*S_ + sub*SUBL];
    uint16_t* d1 = d0 + S_;
#pragma unroll
    for (int q4 = 0; q4 < 4; ++q4) {
        uint4 lo, hi;
        lo.x = (ksave[q4*8+0]&0xffffu) | (ksave[q4*8+1]<<16);
        lo.y = (ksave[q4*8+2]&0xffffu) | (ksave[q4*8+3]<<16);
        lo.z = (ksave[q4*8+4]&0xffffu) | (ksave[q4*8+5]<<16);
        lo.w = (ksave[q4*8+6]&0xffffu) | (ksave[q4*8+7]<<16);
        hi.x = (ksave[q4*8+0]>>16) | (ksave[q4*8+1]&0xffff0000u);
        hi.y = (ksave[q4*8+2]>>16) | (ksave[q4*8+3]&0xffff0000u);
        hi.z = (ksave[q4*8+4]>>16) | (ksave[q4*8+5]&0xffff0000u);
        hi.w = (ksave[q4*8+6]>>16) | (ksave[q4*8+7]&0xffff0000u);
        *(uint4*)&d0[q4*8] = lo;
        *(uint4*)&d1[q4*8] = hi;
    }
}

// ---------------- tables: Pre / Suf / Lam from T, grid (sp,b) ----------------------
__global__ __launch_bounds__(512) void tables(const float* __restrict__ T,
                                              float* __restrict__ Pre,
                                              float* __restrict__ Suf,
                                              float* __restrict__ Lam)
{
    const int sp = blockIdx.x, b = blockIdx.y, dk = threadIdx.x;
    float run = 1.f;
#pragma unroll
    for (int m = 0; m < 8; ++m) {
        Pre[((size_t)b*NSUB + sp*8+m)*D_ + dk] = run;
        run *= T[((size_t)b*NSUB + sp*8+m)*D_ + dk];
    }
    Lam[((size_t)b*NSUP + sp)*D_ + dk] = run;
    float rs = 1.f;
#pragma unroll
    for (int m = 7; m >= 0; --m) {
        rs *= T[((size_t)b*NSUB + sp*8+m)*D_ + dk];
        Suf[((size_t)b*NSUB + sp*8+m)*D_ + dk] = rs;
    }
}

// ---------------- pairsA: flat (i,j) grid, P_ij = Q~_i @ (D_ij * K^_j)^T -----------
__device__ __forceinline__ int swz(int r, int c){ return r*D_ + (c ^ ((r&7)<<3)); }

__global__ __launch_bounds__(256) void pairsA(const uint16_t* __restrict__ Qt,
                                              const uint16_t* __restrict__ Kh,
                                              const float* __restrict__ T,
                                              uint16_t* __restrict__ P)
{
    __shared__ __attribute__((aligned(16))) uint16_t qs[SUBL*D_];
    __shared__ __attribute__((aligned(16))) uint16_t ks[SUBL*D_];
    __shared__ float D_lds[D_];
    const int idx = blockIdx.x, sp = blockIdx.y, b = blockIdx.z;
    int i = 0;
    while (((i+1)*(i+2))/2 <= idx) ++i;
    const int j = idx - (i*(i+1))/2;

    const int tid = threadIdx.x, wave = tid>>6, lane = tid&63;
    const int fr = lane&15, fq = lane>>4;
    const int mq = wave>>1, nq = wave&1;
    const size_t qrow = (size_t)b*S_ + sp*SUPL + i*SUBL;
    const size_t krow = (size_t)b*S_ + sp*SUPL + j*SUBL;
    const size_t prow = ((size_t)(b*NSUP + sp)*SUPL + i*SUBL);

#pragma unroll
    for (int z = 0; z < 8; ++z) {
        int ch = z*256 + tid, r = ch>>6, c = (ch&63)*8;
        *(uint4*)&qs[swz(r,c)] = *(const uint4*)&Qt[(qrow + r)*D_ + c];
    }
    const int dkA = tid*2, dkB = tid*2+1;
    float d0 = 1.f, d1 = 1.f;
    for (int m = j; m < i; ++m) {
        d0 *= T[((size_t)b*NSUB + sp*8 + m)*D_ + dkA];
        d1 *= T[((size_t)b*NSUB + sp*8 + m)*D_ + dkB];
    }
    D_lds[dkA] = d0; D_lds[dkB] = d1;
    __syncthreads();

#pragma unroll
    for (int z = 0; z < 8; ++z) {
        int ch = z*256 + tid, r = ch>>6, c = (ch&63)*8;
        uint4 u = *(const uint4*)&Kh[(krow + r)*D_ + c];
        uint4 o;
        o.x = pack2bf(bflo(u.x)*D_lds[c+0], bfhi(u.x)*D_lds[c+1]);
        o.y = pack2bf(bflo(u.y)*D_lds[c+2], bfhi(u.y)*D_lds[c+3]);
        o.z = pack2bf(bflo(u.z)*D_lds[c+4], bfhi(u.z)*D_lds[c+5]);
        o.w = pack2bf(bflo(u.w)*D_lds[c+6], bfhi(u.w)*D_lds[c+7]);
        *(uint4*)&ks[swz(r,c)] = o;
    }
    __syncthreads();

    f32x4 a0 = {}, a1 = {}, a2 = {}, a3 = {};
#pragma unroll
    for (int kk = 0; kk < 512; kk += 128) {
        bf16x8 q0 = *(const bf16x8*)&qs[swz(mq*16+fr, kk      + fq*8)];
        bf16x8 k0 = *(const bf16x8*)&ks[swz(nq*16+fr, kk      + fq*8)];
        bf16x8 q1 = *(const bf16x8*)&qs[swz(mq*16+fr, kk + 32 + fq*8)];
        bf16x8 k1 = *(const bf16x8*)&ks[swz(nq*16+fr, kk + 32 + fq*8)];
        bf16x8 q2 = *(const bf16x8*)&qs[swz(mq*16+fr, kk + 64 + fq*8)];
        bf16x8 k2 = *(const bf16x8*)&ks[swz(nq*16+fr, kk + 64 + fq*8)];
        bf16x8 q3 = *(const bf16x8*)&qs[swz(mq*16+fr, kk + 96 + fq*8)];
        bf16x8 k3 = *(const bf16x8*)&ks[swz(nq*16+fr, kk + 96 + fq*8)];
        a0 = __builtin_amdgcn_mfma_f32_16x16x32_bf16(q0, k0, a0, 0,0,0);
        a1 = __builtin_amdgcn_mfma_f32_16x16x32_bf16(q1, k1, a1, 0,0,0);
        a2 = __builtin_amdgcn_mfma_f32_16x16x32_bf16(q2, k2, a2, 0,0,0);
        a3 = __builtin_amdgcn_mfma_f32_16x16x32_bf16(q3, k3, a3, 0,0,0);
    }
    const int ul = nq*16 + fr;
#pragma unroll
    for (int q_ = 0; q_ < 4; ++q_) {
        const int tl = mq*16 + fq*4 + q_;
        float v = a0[q_] + a1[q_] + a2[q_] + a3[q_];
        if (i == j && ul > tl) v = 0.f;
        P[(prow + tl)*SUPL + j*SUBL + ul] = f2bf(v);
    }
}

// ---------------- dsgemm: dbuf 2-phase, dS_c = sum_u (Suf*k^_u) v_u^T --------------
__global__ __launch_bounds__(256) void dsgemm(const uint16_t* __restrict__ VT,
                                              const uint16_t* __restrict__ KT,
                                              const float* __restrict__ Suf,
                                              uint16_t* __restrict__ Sst)
{
    __shared__ __attribute__((aligned(16))) uint16_t As[2][128][40];
    __shared__ __attribute__((aligned(16))) uint16_t Bs[2][128][40];
    const int tile = blockIdx.x, c = blockIdx.y, b = blockIdx.z;
    const int m0 = (tile&3)*128, n0 = (tile>>2)*128;
    const int tid = threadIdx.x, wave = tid>>6, lane = tid&63;
    const int wr = (wave>>1)*64, wc = (wave&1)*64;
    const int fr = lane&15, fq = lane>>4;
    f32x4 acc[4][4] = {};

    auto STAGE = [&](int j, int p){
        const int t0 = c*SUPL + j*SUBL;
#pragma unroll
        for (int ch = tid; ch < 512; ch += 256) {
            int row = ch>>2, tc = (ch&3)*8;
            *(uint4*)&As[p][row][tc] = *(const uint4*)&VT[((size_t)b*D_ + m0+row)*S_ + t0 + tc];
        }
#pragma unroll
        for (int ch = tid; ch < 512; ch += 256) {
            int row = ch>>2, tc = (ch&3)*8;
            uint4 u = *(const uint4*)&KT[((size_t)b*D_ + n0+row)*S_ + t0 + tc];
            float sf = Suf[((size_t)b*NSUB + c*8 + j)*D_ + n0 + row];
            uint4 o;
            o.x = pack2bf(bflo(u.x)*sf, bfhi(u.x)*sf);
            o.y = pack2bf(bflo(u.y)*sf, bfhi(u.y)*sf);
            o.z = pack2bf(bflo(u.z)*sf, bfhi(u.z)*sf);
            o.w = pack2bf(bflo(u.w)*sf, bfhi(u.w)*sf);
            *(uint4*)&Bs[p][row][tc] = o;
        }
    };

    STAGE(0, 0);
    __syncthreads();
    int p = 0;
    for (int j = 0; j < 8; ++j) {
        if (j < 7) STAGE(j+1, p^1);
        bf16x8 af[4], bf[4];
#pragma unroll
        for (int m = 0; m < 4; ++m) af[m] = *(const bf16x8*)&As[p][wr+m*16+fr][fq*8];
#pragma unroll
        for (int n = 0; n < 4; ++n) bf[n] = *(const bf16x8*)&Bs[p][wc+n*16+fr][fq*8];
#pragma unroll
        for (int m = 0; m < 4; ++m)
#pragma unroll
            for (int n = 0; n < 4; ++n)
                acc[m][n] = __builtin_amdgcn_mfma_f32_16x16x32_bf16(af[m], bf[n], acc[m][n], 0,0,0);
        __syncthreads();
        p ^= 1;
    }
#pragma unroll
    for (int n = 0; n < 4; ++n) {
        const int dk = n0 + wc + n*16 + fr;
#pragma unroll
        for (int m = 0; m < 4; ++m)
#pragma unroll
            for (int q = 0; q < 4; ++q) {
                const int dv = m0 + wr + m*16 + fq*4 + q;
                Sst[(((size_t)c*B_ + b)*D_ + dv)*D_ + dk] = f2bf(acc[m][n][q]);
            }
    }
}

// ---------------- scanfix: S_c = Lam_c (x) S_{c-1} + dS_c, c = 1..6 ----------------
__global__ __launch_bounds__(256) void scanfix(uint16_t* __restrict__ Sst,
                                               const float* __restrict__ Lam)
{
    const int id = blockIdx.x*256 + threadIdx.x;
    const int g = id & 63, dv = (id>>6) & 511, b = id >> 15;
    const int dk = g*8;
    float s[8];
    {
        uint4 u = *(const uint4*)&Sst[(((size_t)0*B_ + b)*D_ + dv)*D_ + dk];
        s[0]=bflo(u.x); s[1]=bfhi(u.x); s[2]=bflo(u.y); s[3]=bfhi(u.y);
        s[4]=bflo(u.z); s[5]=bfhi(u.z); s[6]=bflo(u.w); s[7]=bfhi(u.w);
    }
    for (int c = 1; c < 7; ++c) {
        const size_t bs = (((size_t)c*B_ + b)*D_ + dv)*D_ + dk;
        uint4 d = *(const uint4*)&Sst[bs];
        float4 l0 = *(const float4*)&Lam[((size_t)b*NSUP + c)*D_ + dk];
        float4 l1 = *(const float4*)&Lam[((size_t)b*NSUP + c)*D_ + dk + 4];
        s[0] = l0.x*s[0] + bflo(d.x); s[1] = l0.y*s[1] + bfhi(d.x);
        s[2] = l0.z*s[2] + bflo(d.y); s[3] = l0.w*s[3] + bfhi(d.y);
        s[4] = l1.x*s[4] + bflo(d.z); s[5] = l1.y*s[5] + bfhi(d.z);
        s[6] = l1.z*s[6] + bflo(d.w); s[7] = l1.w*s[7] + bfhi(d.w);
        uint4 o;
        o.x = pack2bf(s[0],s[1]); o.y = pack2bf(s[2],s[3]);
        o.z = pack2bf(s[4],s[5]); o.w = pack2bf(s[6],s[7]);
        *(uint4*)&Sst[bs] = o;
    }
}

// ---------------- bigout: O = [Q~*Pre | P] @ [S_prev ; V], dbuf, upper-tri masked --
__global__ __launch_bounds__(256) void bigout(const uint16_t* __restrict__ Qt,
                                              const float* __restrict__ Pre,
                                              const uint16_t* __restrict__ Sst,
                                              const uint16_t* __restrict__ Pb,
                                              const uint16_t* __restrict__ VT,
                                              uint16_t* __restrict__ O)
{
    __shared__ __attribute__((aligned(16))) uint16_t SM[2][16384];
    __shared__ float PreL[4*512];
    const int m0 = blockIdx.x*128, n0 = blockIdx.y*128;
    const int b = blockIdx.z>>3, sp = blockIdx.z&7;
    const int tid = threadIdx.x, wave = tid>>6, lane = tid&63;
    const int wr = (wave>>1)*64, wc = (wave&1)*64;
    const int fr = lane&15, fq = lane>>4;
    const int i0 = m0>>5;

#pragma unroll
    for (int z = 0; z < 8; ++z) {
        int idx = z*256 + tid;
        PreL[idx] = Pre[((size_t)b*NSUB + sp*8 + i0 + (idx>>9))*D_ + (idx&511)];
    }
    f32x4 acc[4][4] = {};
    uint4 areg[4];

    auto ISSUE_A = [&](int kt){
        const int k0 = kt*64;
#pragma unroll
        for (int z = 0; z < 4; ++z) {
            int ch = z*256 + tid, r = ch>>3, cc = (ch&7)*8;
            areg[z] = *(const uint4*)&Qt[((size_t)b*S_ + sp*SUPL + m0 + r)*D_ + k0 + cc];
        }
    };
    auto WRITE_A = [&](int kt, int p){
        const int k0 = kt*64;
#pragma unroll
        for (int z = 0; z < 4; ++z) {
            int ch = z*256 + tid, r = ch>>3, cc = (ch&7)*8;
            const float* pr = &PreL[((r>>5)<<9) + k0 + cc];
            uint4 u = areg[z];
            uint4 o;
            o.x = pack2bf(bflo(u.x)*pr[0], bfhi(u.x)*pr[1]);
            o.y = pack2bf(bflo(u.y)*pr[2], bfhi(u.y)*pr[3]);
            o.z = pack2bf(bflo(u.z)*pr[4], bfhi(u.z)*pr[5]);
            o.w = pack2bf(bflo(u.w)*pr[6], bfhi(u.w)*pr[7]);
            *(uint4*)&SM[p][r*64 + (cc ^ ((r&7)<<3))] = o;
        }
    };
    auto STAGE_A_GL = [&](int kt, int p){
        const int u0 = (kt-8)*64;
#pragma unroll
        for (int z = 0; z < 4; ++z) {
            int ch = z*256 + tid, row = ch>>3, kc = ((ch&7) ^ (row&7))*8;
            int ldsb = (z*256 + wave*64)*8;
            gload16(&Pb[((size_t)(b*NSUP + sp)*SUPL + m0 + row)*SUPL + u0 + kc], &SM[p][ldsb]);
        }
    };
    auto STAGE_B = [&](int kt, int p){
        if (kt < 8) {
            const int k0 = kt*64;
#pragma unroll
            for (int z = 0; z < 4; ++z) {
                int ch = z*256 + tid, row = ch>>3, kc = ((ch&7) ^ (row&7))*8;
                int ldsb = (z*256 + wave*64)*8;
                gload16(&Sst[(((size_t)(sp-1)*B_ + b)*D_ + n0 + row)*D_ + k0 + kc], &SM[p][8192+ldsb]);
            }
        } else {
            const int u0 = (kt-8)*64;
#pragma unroll
            for (int z = 0; z < 4; ++z) {
                int ch = z*256 + tid, row = ch>>3, kc = ((ch&7) ^ (row&7))*8;
                int ldsb = (z*256 + wave*64)*8;
                gload16(&VT[((size_t)b*D_ + n0 + row)*S_ + sp*SUPL + u0 + kc], &SM[p][8192+ldsb]);
            }
        }
    };
    auto COMP = [&](int p, int kt){
        const bf16x8 zz = {};
#pragma unroll
        for (int kk = 0; kk < 64; kk += 32) {
            const int sc = (kk + fq*8) ^ ((fr&7)<<3);
            bf16x8 af[4], bfv[4];
#pragma unroll
            for (int m = 0; m < 4; ++m) af[m] = *(const bf16x8*)&SM[p][(wr+m*16+fr)*64 + sc];
            if (kt >= 8) {
                const int jb = ((kt-8)*64 + kk) >> 5;
#pragma unroll
                for (int m = 0; m < 4; ++m) {
                    const int ib = (m0 + wr + m*16) >> 5;
                    if (jb > ib) af[m] = zz;
                }
            }
#pragma unroll
            for (int n = 0; n < 4; ++n) bfv[n] = *(const bf16x8*)&SM[p][8192+(wc+n*16+fr)*64 + sc];
#pragma unroll
            for (int m = 0; m < 4; ++m)
#pragma unroll
                for (int n = 0; n < 4; ++n)
                    acc[m][n] = __builtin_amdgcn_mfma_f32_16x16x32_bf16(af[m], bfv[n], acc[m][n], 0,0,0);
        }
    };

    const int kt0 = (sp == 0) ? 8 : 0;
    if (kt0 < 8) {
        ISSUE_A(kt0);
        STAGE_B(kt0, 0);
        __syncthreads();
        WRITE_A(kt0, 0);
    } else {
        STAGE_A_GL(kt0, 0);
        STAGE_B(kt0, 0);
    }
    __syncthreads();

    int p = 0;
    for (int kt = kt0; kt < 12; ++kt) {
        const int nxt = kt + 1;
        if (nxt < 12) {
            if (nxt < 8) ISSUE_A(nxt); else STAGE_A_GL(nxt, p^1);
            STAGE_B(nxt, p^1);
        }
        COMP(p, kt);
        if (nxt < 12 && nxt < 8) WRITE_A(nxt, p^1);
        __syncthreads();
        p ^= 1;
    }

    uint16_t (*L)[136] = (uint16_t(*)[136])&SM[0][0];
#pragma unroll
    for (int n = 0; n < 4; ++n) {
        const int cl = wc + n*16 + fr;
#pragma unroll
        for (int m = 0; m < 4; ++m)
#pragma unroll
            for (int q = 0; q < 4; ++q)
                L[wr + m*16 + fq*4 + q][cl] = f2bf(acc[m][n][q]);
    }
    __syncthreads();
#pragma unroll
    for (int it = 0; it < 8; ++it) {
        const int r = it*16 + (tid>>4), c8 = (tid&15)*8;
        *(uint4*)&O[((size_t)b*S_ + sp*SUPL + m0 + r)*D_ + n0 + c8] = *(uint4*)&L[r][c8];
    }
}

// ---------------- launch ----------------------------------------------------------
extern "C" void kernel_launch(void* const* d_in, const int* in_sizes, int n_in,
                              void* d_out, int out_size, void* d_ws, size_t ws_size,
                              hipStream_t stream)
{
    (void)in_sizes; (void)n_in; (void)out_size; (void)ws_size;
    const float* x  = (const float*)d_in[0];
    const float* Wq = (const float*)d_in[1];  const float* bq = (const float*)d_in[2];
    const float* Wk = (const float*)d_in[3];  const float* bk = (const float*)d_in[4];
    const float* Wv = (const float*)d_in[5];  const float* bv = (const float*)d_in[6];
    const float* Wg = (const float*)d_in[7];  const float* bg = (const float*)d_in[8];
    const float* Wo = (const float*)d_in[9];  const float* bo = (const float*)d_in[10];

    char* w = (char*)d_ws;
    const size_t MD2 = (size_t)M_*D_*2;
    uint16_t* Wb = (uint16_t*)w;                       w += 5*(size_t)D_*D_*2;
    uint16_t* xb = (uint16_t*)w;                       w += MD2;                  // x, later O
    uint16_t* Qb = (uint16_t*)w;                       w += MD2;                  // Q -> Q~
    uint16_t* Kb = (uint16_t*)w;                       w += MD2;                  // K -> K^ rows
    uint16_t* KT = (uint16_t*)w;                       w += MD2;                  // K^T [b][dk][t]
    uint16_t* VT = (uint16_t*)w;                       w += MD2;                  // V^T [b][dv][t]
    uint16_t* Gb = (uint16_t*)w;                       w += MD2;                  // gamma bf16
    uint16_t* Sst = (uint16_t*)w;                      w += (size_t)7*B_*D_*D_*2;
    uint16_t* Pb  = (uint16_t*)w;                      w += (size_t)B_*NSUP*SUPL*SUPL*2;
    float*    T   = (float*)w;                         w += (size_t)B_*NSUB*D_*4;
    float*    Pre = (float*)w;                         w += (size_t)B_*NSUB*D_*4;
    float*    Suf = (float*)w;                         w += (size_t)B_*NSUB*D_*4;
    float*    Lam = (float*)w;                         w += (size_t)B_*NSUP*D_*4;

    convall<<<dim3(4096 + 5*128), 256, 0, stream>>>(x, Wq, Wk, Wv, Wg, Wo, xb, Wb);

    proj4<<<dim3(M_/128, 16), 256, 0, stream>>>(xb, Wb, bq, bk, bv, bg, Qb, Kb, VT, Gb);

    prep<<<dim3(NSUB, B_), 256, 0, stream>>>(Gb, Qb, Kb, KT, T);
    tables<<<dim3(NSUP, B_), 512, 0, stream>>>(T, Pre, Suf, Lam);

    pairsA<<<dim3(36, NSUP, B_), 256, 0, stream>>>(Qb, Kb, T, Pb);
    dsgemm<<<dim3(16, 7, B_), 256, 0, stream>>>(VT, KT, Suf, Sst);
    scanfix<<<dim3(1024), 256, 0, stream>>>(Sst, Lam);

    bigout<<<dim3(2, 4, B_*NSUP), 256, 0, stream>>>(Qb, Pre, Sst, Pb, VT, xb);

    mfma_gemm<<<dim3(M_/128, D_/128), 256, 0, stream>>>(xb, Wb + 4*(size_t)D_*D_, bo, (float*)d_out);
}